// Round 7
// baseline (540.035 us; speedup 1.0000x reference)
//
#include <hip/hip_runtime.h>
#include <hip/hip_cooperative_groups.h>
#include <math.h>

namespace cg = cooperative_groups;

#define D 512

__device__ __forceinline__ float dot4(float4 a, float4 b) {
    return a.x*b.x + a.y*b.y + a.z*b.z + a.w*b.w;
}
__device__ __forceinline__ float wave_red_sum(float v) {
    #pragma unroll
    for (int off = 32; off; off >>= 1) v += __shfl_down(v, off);
    return v;
}
__device__ __forceinline__ float wave_red_max(float v) {
    #pragma unroll
    for (int off = 32; off; off >>= 1) v = fmaxf(v, __shfl_down(v, off));
    return v;
}

__global__ __launch_bounds__(256, 4) void k_fused(
    const float* __restrict__ f, const float* __restrict__ w,
    const float* __restrict__ bptr, const int* __restrict__ kptr,
    float* __restrict__ dot, float* __restrict__ scores,
    float* __restrict__ u, float* __restrict__ pmax, float* __restrict__ psum,
    float* __restrict__ partial, float* __restrict__ bag,
    float* __restrict__ w_out, int n)
{
    cg::grid_group grid = cg::this_grid();
    const int g    = gridDim.x;
    const int lane = threadIdx.x & 63;
    const int wid  = threadIdx.x >> 6;
    __shared__ float sm[4];
    __shared__ float sh_scal[2];

    // ---------- phase 1: dot[r] = f[r].w  (R1/R5-proven wave-per-row) ------
    {
        const float4* wr = (const float4*)w;
        float4 b0 = wr[lane], b1 = wr[lane + 64];
        int nwaves = g * 4;
        int wgid   = blockIdx.x * 4 + wid;
        int rpw    = (n + nwaves - 1) / nwaves;
        int r0 = wgid * rpw;
        int r1 = min(r0 + rpw, n);
        for (int row = r0; row < r1; ++row) {
            const float4* fr = (const float4*)(f + (size_t)row * D);
            float s = dot4(fr[lane], b0) + dot4(fr[lane + 64], b1);
            s = wave_red_sum(s);
            if (lane == 0) dot[row] = s;
        }
    }
    grid.sync();

    // ---------- phase 2: scores + per-block softmax partials ---------------
    {
        int k = *kptr;
        float bias = bptr[0];
        int gid = blockIdx.x * 256 + threadIdx.x;
        int gstride = g * 256;
        float mloc = -INFINITY;
        for (int j = gid; j < n; j += gstride) {
            int lo = max(j - k, 0), hi = min(j + k, n - 1);
            float s = 0.f;
            for (int q = lo; q <= hi; ++q) s += dot[q];
            float val = s / (float)(hi - lo + 1) + bias;
            scores[j] = val;
            mloc = fmaxf(mloc, val);
        }
        float m = wave_red_max(mloc);
        if (lane == 0) sm[wid] = m;
        __syncthreads();
        if (threadIdx.x == 0)
            sh_scal[0] = fmaxf(fmaxf(sm[0], sm[1]), fmaxf(sm[2], sm[3]));
        __syncthreads();
        float bmax = sh_scal[0];
        float eloc = 0.f;
        for (int j = gid; j < n; j += gstride)
            eloc += __expf(scores[j] - bmax);
        float e = wave_red_sum(eloc);
        __syncthreads();               // sm reuse guard
        if (lane == 0) sm[wid] = e;
        __syncthreads();
        if (threadIdx.x == 0) {
            pmax[blockIdx.x] = bmax;
            psum[blockIdx.x] = sm[0] + sm[1] + sm[2] + sm[3];
        }
    }
    grid.sync();

    // ---------- phase 3: redundant combine + w_out / u ---------------------
    {
        float m = -INFINITY;
        for (int idx = threadIdx.x; idx < g; idx += 256) m = fmaxf(m, pmax[idx]);
        m = wave_red_max(m);
        if (lane == 0) sm[wid] = m;
        __syncthreads();
        if (threadIdx.x == 0)
            sh_scal[0] = fmaxf(fmaxf(sm[0], sm[1]), fmaxf(sm[2], sm[3]));
        __syncthreads();
        float gmax = sh_scal[0];
        float s = 0.f;
        for (int idx = threadIdx.x; idx < g; idx += 256)
            s += psum[idx] * __expf(pmax[idx] - gmax);
        s = wave_red_sum(s);
        __syncthreads();               // sm reuse guard
        if (lane == 0) sm[wid] = s;
        __syncthreads();
        if (threadIdx.x == 0)
            sh_scal[1] = 1.f / (sm[0] + sm[1] + sm[2] + sm[3]);
        __syncthreads();
        float inv = sh_scal[1];

        int k = *kptr;
        int gid = blockIdx.x * 256 + threadIdx.x;
        int gstride = g * 256;
        for (int j = gid; j < n; j += gstride) {
            float ej = __expf(scores[j] - gmax);
            w_out[j] = ej * inv;
            int lo = max(j - k, 0), hi = min(j + k, n - 1);
            float acc = 0.f;
            for (int i = lo; i <= hi; ++i) {
                int li = max(i - k, 0), hh = min(i + k, n - 1);
                float e = __expf(scores[i] - gmax);
                acc += e * __builtin_amdgcn_rcpf((float)(hh - li + 1));
            }
            u[j] = acc * inv;
        }
    }
    grid.sync();

    // ---------- phase 4: partial bag (R5-proven inner loop, 2 sub-blocks) --
    {
        int t  = threadIdx.x & 127;            // float4 col (128 x 4 = 512)
        int sb = blockIdx.x * 2 + (threadIdx.x >> 7);
        int NBP = g * 2;
        int chunk = (n + NBP - 1) / NBP;
        int j0 = sb * chunk;
        int j1 = min(j0 + chunk, n);
        float4 acc = make_float4(0.f, 0.f, 0.f, 0.f);
        for (int j = j0; j < j1; ++j) {
            float uj = u[j];
            float4 v = ((const float4*)(f + (size_t)j * D))[t];
            acc.x += uj * v.x; acc.y += uj * v.y;
            acc.z += uj * v.z; acc.w += uj * v.w;
        }
        ((float4*)(partial + (size_t)sb * D))[t] = acc;
    }
    grid.sync();

    // ---------- phase 5: reduce partial[NBP][512] -> bag (blocks 0..31) ----
    if (blockIdx.x < 32) {
        int NBP = g * 2;
        int c = blockIdx.x * 16 + (threadIdx.x & 15);
        int r = threadIdx.x >> 4;
        float acc = 0.f;
        for (int b = r; b < NBP; b += 16) acc += partial[(size_t)b * D + c];
        __shared__ float sred[256];
        sred[threadIdx.x] = acc;
        __syncthreads();
        if (threadIdx.x < 16) {
            float s = 0.f;
            #pragma unroll
            for (int q = 0; q < 16; ++q) s += sred[q * 16 + threadIdx.x];
            bag[blockIdx.x * 16 + threadIdx.x] = s;
        }
    }
}

extern "C" void kernel_launch(void* const* d_in, const int* in_sizes, int n_in,
                              void* d_out, int out_size, void* d_ws, size_t ws_size,
                              hipStream_t stream) {
    const float* f  = (const float*)d_in[0];
    const float* aw = (const float*)d_in[1];
    const float* ab = (const float*)d_in[2];
    const int*   kp = (const int*)d_in[3];
    int n = in_sizes[0] / D;

    float* bag   = (float*)d_out;        // [512]
    float* w_out = (float*)d_out + D;    // [n]

    // grid: co-resident blocks only (cooperative requirement). 256 CUs.
    int occ = 0;
    hipOccupancyMaxActiveBlocksPerMultiprocessor(&occ, k_fused, 256, 0);
    int grid = occ * 256;
    if (grid > 1024) grid = 1024;
    if (grid < 64)   grid = 64;          // paranoia floor (still grid-stride-correct)

    // workspace layout (sized for grid up to 1024 -> NBP up to 2048)
    float* wsf     = (float*)d_ws;
    float* dot     = wsf;                          // n
    float* scores  = wsf + n;                      // n
    float* u       = wsf + 2 * (size_t)n;          // n
    float* pmax    = wsf + 3 * (size_t)n;          // <=1024
    float* psum    = pmax + 1024;                  // <=1024
    size_t poff    = ((3 * (size_t)n + 2048) + 31) & ~(size_t)31;
    float* partial = wsf + poff;                   // <= 2048 * 512

    void* args[] = { (void*)&f, (void*)&aw, (void*)&ab, (void*)&kp,
                     (void*)&dot, (void*)&scores, (void*)&u,
                     (void*)&pmax, (void*)&psum, (void*)&partial,
                     (void*)&bag, (void*)&w_out, (void*)&n };

    hipLaunchCooperativeKernel((const void*)k_fused, dim3(grid), dim3(256),
                               args, 0, stream);
}

// Round 8
// 147.916 us; speedup vs baseline: 3.6509x; 3.6509x over previous
//
#include <hip/hip_runtime.h>
#include <math.h>

#define D 512

// ---------------- K1: dot[j] = features[j] . attn_w  (one wave per row) ----
// R1-proven version: 4 waves/block, 1 row per wave. DO NOT TOUCH.
__global__ void k_dot(const float* __restrict__ f, const float* __restrict__ w,
                      float* __restrict__ dot, int n) {
    int wave = threadIdx.x >> 6;            // 4 waves / block
    int lane = threadIdx.x & 63;
    int row  = blockIdx.x * 4 + wave;
    if (row >= n) return;
    const float4* fr = (const float4*)(f + (size_t)row * D);
    const float4* wr = (const float4*)w;
    float4 a0 = fr[lane],      b0 = wr[lane];
    float4 a1 = fr[lane + 64], b1 = wr[lane + 64];
    float s = a0.x*b0.x + a0.y*b0.y + a0.z*b0.z + a0.w*b0.w
            + a1.x*b1.x + a1.y*b1.y + a1.z*b1.z + a1.w*b1.w;
    #pragma unroll
    for (int off = 32; off; off >>= 1) s += __shfl_down(s, off);
    if (lane == 0) dot[row] = s;
}

// ------- K2: scores + per-block softmax partials (m_b, s_b) ----------------
__global__ void k_scores(const float* __restrict__ dot, const float* __restrict__ bptr,
                         const int* __restrict__ kptr, float* __restrict__ scores,
                         float* __restrict__ pmax, float* __restrict__ psum, int n) {
    int i = blockIdx.x * 256 + threadIdx.x;
    int k = *kptr;
    float val = -INFINITY;
    if (i < n) {
        int lo = max(i - k, 0), hi = min(i + k, n - 1);
        float s = 0.f;
        for (int j = lo; j <= hi; ++j) s += dot[j];
        val = s / (float)(hi - lo + 1) + bptr[0];
        scores[i] = val;
    }
    __shared__ float sm[4];
    __shared__ float bmax;
    int lane = threadIdx.x & 63, wid = threadIdx.x >> 6;
    float m = val;
    #pragma unroll
    for (int off = 32; off; off >>= 1) m = fmaxf(m, __shfl_down(m, off));
    if (lane == 0) sm[wid] = m;
    __syncthreads();
    if (threadIdx.x == 0)
        bmax = fmaxf(fmaxf(sm[0], sm[1]), fmaxf(sm[2], sm[3]));
    __syncthreads();
    float mb = bmax;
    float e = (i < n) ? __expf(val - mb) : 0.f;
    #pragma unroll
    for (int off = 32; off; off >>= 1) e += __shfl_down(e, off);
    __syncthreads();               // sm reuse guard
    if (lane == 0) sm[wid] = e;
    __syncthreads();
    if (threadIdx.x == 0) {
        pmax[blockIdx.x] = mb;
        psum[blockIdx.x] = sm[0] + sm[1] + sm[2] + sm[3];
    }
}

// ---- K3: inline-combine partials, then w[j] and u[j] ------------------------
// u[j] = inv * sum_{i in win(j)} exp(scores[i]-gmax)/cnt(i)
__global__ void k_wu(const float* __restrict__ scores, const float* __restrict__ pmax,
                     const float* __restrict__ psum, int nb1,
                     const int* __restrict__ kptr, float* __restrict__ w_out,
                     float* __restrict__ u, int n) {
    __shared__ float sm[4];
    __shared__ float gshared[2];
    int lane = threadIdx.x & 63, wid = threadIdx.x >> 6;

    // global max (each block redundantly reduces nb1 entries — L2-hit, ~3 KB)
    float m = -INFINITY;
    for (int idx = threadIdx.x; idx < nb1; idx += 256) m = fmaxf(m, pmax[idx]);
    #pragma unroll
    for (int off = 32; off; off >>= 1) m = fmaxf(m, __shfl_down(m, off));
    if (lane == 0) sm[wid] = m;
    __syncthreads();
    if (threadIdx.x == 0)
        gshared[0] = fmaxf(fmaxf(sm[0], sm[1]), fmaxf(sm[2], sm[3]));
    __syncthreads();
    float gmax = gshared[0];

    // global sum
    float s = 0.f;
    for (int idx = threadIdx.x; idx < nb1; idx += 256)
        s += psum[idx] * __expf(pmax[idx] - gmax);
    #pragma unroll
    for (int off = 32; off; off >>= 1) s += __shfl_down(s, off);
    __syncthreads();               // sm reuse guard
    if (lane == 0) sm[wid] = s;
    __syncthreads();
    if (threadIdx.x == 0)
        gshared[1] = 1.f / (sm[0] + sm[1] + sm[2] + sm[3]);
    __syncthreads();
    float inv = gshared[1];

    int j = blockIdx.x * 256 + threadIdx.x;
    if (j >= n) return;
    int k = *kptr;
    float ej = __expf(scores[j] - gmax);
    w_out[j] = ej * inv;
    int lo = max(j - k, 0), hi = min(j + k, n - 1);
    float acc = 0.f;
    for (int i = lo; i <= hi; ++i) {
        int li = max(i - k, 0), hh = min(i + k, n - 1);
        float e = __expf(scores[i] - gmax);
        acc += e * __builtin_amdgcn_rcpf((float)(hh - li + 1));
    }
    u[j] = acc * inv;
}

// ---------------- K4: partial bag per block (R1-proven simple loop) ---------
// ONLY the block count changes vs R5 (NB_P 1000 -> 4096); loop is identical.
__global__ void k_pbag(const float* __restrict__ f, const float* __restrict__ u,
                       float* __restrict__ partial, int n, int chunk) {
    int t = threadIdx.x;                         // 128 threads, float4 each = 512 cols
    int j0 = blockIdx.x * chunk;
    int j1 = min(j0 + chunk, n);
    float4 acc = make_float4(0.f, 0.f, 0.f, 0.f);
    for (int j = j0; j < j1; ++j) {
        float uj = u[j];
        float4 v = ((const float4*)(f + (size_t)j * D))[t];
        acc.x += uj * v.x; acc.y += uj * v.y;
        acc.z += uj * v.z; acc.w += uj * v.w;
    }
    ((float4*)(partial + (size_t)blockIdx.x * D))[t] = acc;
}

// ---------------- K5: reduce partial[nb][512] -> bag[512] -------------------
__global__ void k_rbag(const float* __restrict__ partial, float* __restrict__ bag, int nb) {
    int c = blockIdx.x * 16 + (threadIdx.x & 15);   // 32 blocks x 16 cols
    int r = threadIdx.x >> 4;                       // 16 row-groups
    float acc = 0.f;
    for (int b = r; b < nb; b += 16) acc += partial[(size_t)b * D + c];
    __shared__ float sm[256];
    sm[threadIdx.x] = acc;
    __syncthreads();
    if (threadIdx.x < 16) {
        float s = 0.f;
        #pragma unroll
        for (int q = 0; q < 16; ++q) s += sm[q * 16 + threadIdx.x];
        bag[blockIdx.x * 16 + threadIdx.x] = s;
    }
}

extern "C" void kernel_launch(void* const* d_in, const int* in_sizes, int n_in,
                              void* d_out, int out_size, void* d_ws, size_t ws_size,
                              hipStream_t stream) {
    const float* f  = (const float*)d_in[0];
    const float* aw = (const float*)d_in[1];
    const float* ab = (const float*)d_in[2];
    const int*   kp = (const int*)d_in[3];
    int n = in_sizes[0] / D;

    float* bag   = (float*)d_out;        // [512]
    float* w_out = (float*)d_out + D;    // [n]

    int nb2 = (n + 255) / 256;           // 391 blocks for scores / wu

    float* wsf     = (float*)d_ws;
    float* dot     = wsf;                        // n
    float* scores  = wsf + n;                    // n
    float* u       = wsf + 2 * (size_t)n;        // n
    float* pmax    = wsf + 3 * (size_t)n;        // nb2
    float* psum    = pmax + nb2;                 // nb2
    size_t poff    = ((3 * (size_t)n + 2 * (size_t)nb2) + 31) & ~(size_t)31;
    float* partial = wsf + poff;                 // NB_P * D

    // NB_P = 4096 if workspace allows (9.5 MB), else proven 2048/1000 fallback
    size_t avail_f = ws_size / sizeof(float);
    int NB_P = 4096;
    while (NB_P > 1000 && poff + (size_t)NB_P * D > avail_f) NB_P >>= 1;

    int chunk = (n + NB_P - 1) / NB_P;

    k_dot   <<<(n + 3) / 4, 256, 0, stream>>>(f, aw, dot, n);
    k_scores<<<nb2, 256, 0, stream>>>(dot, ab, kp, scores, pmax, psum, n);
    k_wu    <<<nb2, 256, 0, stream>>>(scores, pmax, psum, nb2, kp, w_out, u, n);
    k_pbag  <<<NB_P, 128, 0, stream>>>(f, u, partial, n, chunk);
    k_rbag  <<<32, 256, 0, stream>>>(partial, bag, NB_P);
}

// Round 9
// 90.742 us; speedup vs baseline: 5.9513x; 1.6301x over previous
//
#include <hip/hip_runtime.h>
#include <math.h>

#define D 512
#define NB_P 1000   // partial-bag blocks — R5-proven; DO NOT CHANGE (R8: 4096 = +52us)

// ---------------- K1: dot[j] = features[j] . attn_w  (one wave per row) ----
// R1/R5-proven version: 4 waves/block, 1 row per wave. DO NOT TOUCH.
__global__ void k_dot(const float* __restrict__ f, const float* __restrict__ w,
                      float* __restrict__ dot, int n) {
    int wave = threadIdx.x >> 6;            // 4 waves / block
    int lane = threadIdx.x & 63;
    int row  = blockIdx.x * 4 + wave;
    if (row >= n) return;
    const float4* fr = (const float4*)(f + (size_t)row * D);
    const float4* wr = (const float4*)w;
    float4 a0 = fr[lane],      b0 = wr[lane];
    float4 a1 = fr[lane + 64], b1 = wr[lane + 64];
    float s = a0.x*b0.x + a0.y*b0.y + a0.z*b0.z + a0.w*b0.w
            + a1.x*b1.x + a1.y*b1.y + a1.z*b1.z + a1.w*b1.w;
    #pragma unroll
    for (int off = 32; off; off >>= 1) s += __shfl_down(s, off);
    if (lane == 0) dot[row] = s;
}

// ------- K2: scores + per-block softmax partials (m_b, s_b) ----------------
__global__ void k_scores(const float* __restrict__ dot, const float* __restrict__ bptr,
                         const int* __restrict__ kptr, float* __restrict__ scores,
                         float* __restrict__ pmax, float* __restrict__ psum, int n) {
    int i = blockIdx.x * 256 + threadIdx.x;
    int k = *kptr;
    float val = -INFINITY;
    if (i < n) {
        int lo = max(i - k, 0), hi = min(i + k, n - 1);
        float s = 0.f;
        for (int j = lo; j <= hi; ++j) s += dot[j];
        val = s / (float)(hi - lo + 1) + bptr[0];
        scores[i] = val;
    }
    __shared__ float sm[4];
    __shared__ float bmax;
    int lane = threadIdx.x & 63, wid = threadIdx.x >> 6;
    float m = val;
    #pragma unroll
    for (int off = 32; off; off >>= 1) m = fmaxf(m, __shfl_down(m, off));
    if (lane == 0) sm[wid] = m;
    __syncthreads();
    if (threadIdx.x == 0)
        bmax = fmaxf(fmaxf(sm[0], sm[1]), fmaxf(sm[2], sm[3]));
    __syncthreads();
    float mb = bmax;
    float e = (i < n) ? __expf(val - mb) : 0.f;
    #pragma unroll
    for (int off = 32; off; off >>= 1) e += __shfl_down(e, off);
    __syncthreads();               // sm reuse guard
    if (lane == 0) sm[wid] = e;
    __syncthreads();
    if (threadIdx.x == 0) {
        pmax[blockIdx.x] = mb;
        psum[blockIdx.x] = sm[0] + sm[1] + sm[2] + sm[3];
    }
}

// ---- K3: inline-combine partials, then w[j] and u[j] ------------------------
// u[j] = inv * sum_{i in win(j)} exp(scores[i]-gmax)/cnt(i)
__global__ void k_wu(const float* __restrict__ scores, const float* __restrict__ pmax,
                     const float* __restrict__ psum, int nb1,
                     const int* __restrict__ kptr, float* __restrict__ w_out,
                     float* __restrict__ u, int n) {
    __shared__ float sm[4];
    __shared__ float gshared[2];
    int lane = threadIdx.x & 63, wid = threadIdx.x >> 6;

    // global max (each block redundantly reduces nb1 entries — L2-hit, ~3 KB)
    float m = -INFINITY;
    for (int idx = threadIdx.x; idx < nb1; idx += 256) m = fmaxf(m, pmax[idx]);
    #pragma unroll
    for (int off = 32; off; off >>= 1) m = fmaxf(m, __shfl_down(m, off));
    if (lane == 0) sm[wid] = m;
    __syncthreads();
    if (threadIdx.x == 0)
        gshared[0] = fmaxf(fmaxf(sm[0], sm[1]), fmaxf(sm[2], sm[3]));
    __syncthreads();
    float gmax = gshared[0];

    // global sum
    float s = 0.f;
    for (int idx = threadIdx.x; idx < nb1; idx += 256)
        s += psum[idx] * __expf(pmax[idx] - gmax);
    #pragma unroll
    for (int off = 32; off; off >>= 1) s += __shfl_down(s, off);
    __syncthreads();               // sm reuse guard
    if (lane == 0) sm[wid] = s;
    __syncthreads();
    if (threadIdx.x == 0)
        gshared[1] = 1.f / (sm[0] + sm[1] + sm[2] + sm[3]);
    __syncthreads();
    float inv = gshared[1];

    int j = blockIdx.x * 256 + threadIdx.x;
    if (j >= n) return;
    int k = *kptr;
    float ej = __expf(scores[j] - gmax);
    w_out[j] = ej * inv;
    int lo = max(j - k, 0), hi = min(j + k, n - 1);
    float acc = 0.f;
    for (int i = lo; i <= hi; ++i) {
        int li = max(i - k, 0), hh = min(i + k, n - 1);
        float e = __expf(scores[i] - gmax);
        acc += e * __builtin_amdgcn_rcpf((float)(hh - li + 1));
    }
    u[j] = acc * inv;
}

// ---- K4: partial bag — SAME geometry as R5 (1000 blocks x 128 thr, 100 rows
// contiguous per block); ONLY change: unroll x4 with 4 independent
// accumulators so each wave keeps ~8 loads in flight (8 KB contiguous/iter).
__global__ void k_pbag(const float* __restrict__ f, const float* __restrict__ u,
                       float* __restrict__ partial, int n, int chunk) {
    int t = threadIdx.x;                         // 128 threads, float4 each = 512 cols
    int j0 = blockIdx.x * chunk;
    int j1 = min(j0 + chunk, n);
    float4 acc0 = make_float4(0.f,0.f,0.f,0.f);
    float4 acc1 = make_float4(0.f,0.f,0.f,0.f);
    float4 acc2 = make_float4(0.f,0.f,0.f,0.f);
    float4 acc3 = make_float4(0.f,0.f,0.f,0.f);
    int j = j0;
    for (; j + 4 <= j1; j += 4) {
        float u0 = u[j], u1 = u[j+1], u2 = u[j+2], u3 = u[j+3];
        float4 v0 = ((const float4*)(f + (size_t)(j  ) * D))[t];
        float4 v1 = ((const float4*)(f + (size_t)(j+1) * D))[t];
        float4 v2 = ((const float4*)(f + (size_t)(j+2) * D))[t];
        float4 v3 = ((const float4*)(f + (size_t)(j+3) * D))[t];
        acc0.x += u0*v0.x; acc0.y += u0*v0.y; acc0.z += u0*v0.z; acc0.w += u0*v0.w;
        acc1.x += u1*v1.x; acc1.y += u1*v1.y; acc1.z += u1*v1.z; acc1.w += u1*v1.w;
        acc2.x += u2*v2.x; acc2.y += u2*v2.y; acc2.z += u2*v2.z; acc2.w += u2*v2.w;
        acc3.x += u3*v3.x; acc3.y += u3*v3.y; acc3.z += u3*v3.z; acc3.w += u3*v3.w;
    }
    for (; j < j1; ++j) {
        float uj = u[j];
        float4 v = ((const float4*)(f + (size_t)j * D))[t];
        acc0.x += uj*v.x; acc0.y += uj*v.y; acc0.z += uj*v.z; acc0.w += uj*v.w;
    }
    float4 a;
    a.x = (acc0.x + acc1.x) + (acc2.x + acc3.x);
    a.y = (acc0.y + acc1.y) + (acc2.y + acc3.y);
    a.z = (acc0.z + acc1.z) + (acc2.z + acc3.z);
    a.w = (acc0.w + acc1.w) + (acc2.w + acc3.w);
    ((float4*)(partial + (size_t)blockIdx.x * D))[t] = a;
}

// ---------------- K5: reduce partial[nb][512] -> bag[512] -------------------
__global__ void k_rbag(const float* __restrict__ partial, float* __restrict__ bag, int nb) {
    int c = blockIdx.x * 16 + (threadIdx.x & 15);   // 32 blocks x 16 cols
    int r = threadIdx.x >> 4;                       // 16 row-groups
    float acc = 0.f;
    for (int b = r; b < nb; b += 16) acc += partial[(size_t)b * D + c];
    __shared__ float sm[256];
    sm[threadIdx.x] = acc;
    __syncthreads();
    if (threadIdx.x < 16) {
        float s = 0.f;
        #pragma unroll
        for (int q = 0; q < 16; ++q) s += sm[q * 16 + threadIdx.x];
        bag[blockIdx.x * 16 + threadIdx.x] = s;
    }
}

extern "C" void kernel_launch(void* const* d_in, const int* in_sizes, int n_in,
                              void* d_out, int out_size, void* d_ws, size_t ws_size,
                              hipStream_t stream) {
    const float* f  = (const float*)d_in[0];
    const float* aw = (const float*)d_in[1];
    const float* ab = (const float*)d_in[2];
    const int*   kp = (const int*)d_in[3];
    int n = in_sizes[0] / D;

    float* bag   = (float*)d_out;        // [512]
    float* w_out = (float*)d_out + D;    // [n]

    int nb2 = (n + 255) / 256;           // 391 blocks for scores / wu

    float* wsf     = (float*)d_ws;
    float* dot     = wsf;                        // n
    float* scores  = wsf + n;                    // n
    float* u       = wsf + 2 * (size_t)n;        // n
    float* pmax    = wsf + 3 * (size_t)n;        // nb2
    float* psum    = pmax + nb2;                 // nb2
    size_t poff    = ((3 * (size_t)n + 2 * (size_t)nb2) + 31) & ~(size_t)31;
    float* partial = wsf + poff;                 // NB_P * D

    int chunk = (n + NB_P - 1) / NB_P;

    k_dot   <<<(n + 3) / 4, 256, 0, stream>>>(f, aw, dot, n);
    k_scores<<<nb2, 256, 0, stream>>>(dot, ab, kp, scores, pmax, psum, n);
    k_wu    <<<nb2, 256, 0, stream>>>(scores, pmax, psum, nb2, kp, w_out, u, n);
    k_pbag  <<<NB_P, 128, 0, stream>>>(f, u, partial, n, chunk);
    k_rbag  <<<32, 256, 0, stream>>>(partial, bag, NB_P);
}